// Round 10
// baseline (265.654 us; speedup 1.0000x reference)
//
#include <hip/hip_runtime.h>
#include <hip/hip_bf16.h>

#define DD 128    // feature dim
#define HH 16     // hidden dim
#define BW 128    // bucket width (nodes per bucket) = 1<<7
#define NBMAX 1024
#define SCAP 4096      // LDS slice cap in sortagg (avg slice 2048, max ~2300)

// bf16x2 pack/unpack (RNE)
__device__ __forceinline__ float lo16(unsigned u) { return __uint_as_float(u << 16); }
__device__ __forceinline__ float hi16(unsigned u) { return __uint_as_float(u & 0xffff0000u); }
__device__ __forceinline__ unsigned b16(float f) {
    unsigned u = __float_as_uint(f);
    return (u + 0x7fffu + ((u >> 16) & 1u)) >> 16;
}
__device__ __forceinline__ unsigned pack2(float a, float b) {
    return b16(a) | (b16(b) << 16);
}

// ---------------------------------------------------------------------------
// K_build: single-kernel CSR-bucket build.
//   blocks [0, cblocks): phase 1 — LDS hist of own 4096-edge chunk (dst kept
//     in regs), add to global bcnt, ticket. Last-arriving block scans bcnt ->
//     bstart/gcursor (+bstart[NB]=E, nodestart[N]=E) and releases scan_done.
//     phase 2 — bulk-reserve per-bucket ranges from gcursor, scatter packed
//     entries (local<<20 | src).
//   block cblocks: classifier-collapse prep:
//     wsu[0..15]=w2_l[j,:].wc[:128]  wsu[16..31]=w2_l[j,:].wc[128:]
//     wsu[32..47]=w2_r[j,:].wc[:128] wsu[48..63]=w2_r[j,:].wc[128:]
//     wsu[64]=b2.wc[:128]+bc ; wsu[65]=b2.wc[128:]
// Co-residency: 392 blocks x 256thr, 8KB LDS -> 2048 slots >> 392 (safe).
// ---------------------------------------------------------------------------
__global__ __launch_bounds__(256) void k_build(
    const int* __restrict__ src, const int* __restrict__ dst,
    int* __restrict__ bcnt, int* __restrict__ bstart,
    int* __restrict__ gcursor, int* __restrict__ nodestart,
    int* __restrict__ packed, int* __restrict__ ticket2,
    int* __restrict__ scan_done,
    int E4, int NB, int cblocks, int N, int E,
    const float* __restrict__ w2l, const float* __restrict__ w2r,
    const float* __restrict__ b2v, const float* __restrict__ wc,
    const float* __restrict__ bc, float* __restrict__ wsu) {
    const int tid = threadIdx.x;

    if (blockIdx.x == (unsigned)cblocks) {      // ---- prep role ----
        if (tid < 64) {
            int k = tid >> 4, j = tid & 15;
            const float* W = (k < 2) ? w2l : w2r;
            int off = (k & 1) * DD;
            float s = 0.f;
            for (int d = 0; d < DD; ++d) s += W[j * DD + d] * wc[off + d];
            wsu[k * 16 + j] = s;
        } else if (tid == 64) {
            float s = bc[0];
            for (int d = 0; d < DD; ++d) s += b2v[d] * wc[d];
            wsu[64] = s;
        } else if (tid == 65) {
            float s = 0.f;
            for (int d = 0; d < DD; ++d) s += b2v[d] * wc[DD + d];
            wsu[65] = s;
        }
        return;
    }

    __shared__ int hist[NBMAX];
    __shared__ int cur[NBMAX];
    __shared__ int wsum[4];
    __shared__ int winner;

    for (int i = tid; i < NB; i += 256) hist[i] = 0;
    __syncthreads();

    const int base = blockIdx.x * 1024;
    int4 dreg[4];
#pragma unroll
    for (int k = 0; k < 4; ++k) {
        int i4 = base + k * 256 + tid;
        if (i4 < E4) {
            int4 d = ((const int4*)dst)[i4];
            dreg[k] = d;
            atomicAdd(&hist[d.x >> 7], 1);
            atomicAdd(&hist[d.y >> 7], 1);
            atomicAdd(&hist[d.z >> 7], 1);
            atomicAdd(&hist[d.w >> 7], 1);
        }
    }
    __syncthreads();
    for (int i = tid; i < NB; i += 256) {
        int h = hist[i];
        if (h) atomicAdd(&bcnt[i], h);
    }
    __threadfence();
    if (tid == 0) winner = (atomicAdd(ticket2, 1) == cblocks - 1) ? 1 : 0;
    __syncthreads();

    if (winner) {
        // all blocks' bcnt adds are visible (they fenced before ticket)
        __threadfence();
        int idx0 = tid * 4;
        int v0 = (idx0 + 0 < NB) ? atomicAdd(&bcnt[idx0 + 0], 0) : 0;
        int v1 = (idx0 + 1 < NB) ? atomicAdd(&bcnt[idx0 + 1], 0) : 0;
        int v2 = (idx0 + 2 < NB) ? atomicAdd(&bcnt[idx0 + 2], 0) : 0;
        int v3 = (idx0 + 3 < NB) ? atomicAdd(&bcnt[idx0 + 3], 0) : 0;
        int tsum = v0 + v1 + v2 + v3;
        int lane = tid & 63, w = tid >> 6;
        int s = tsum;
#pragma unroll
        for (int off = 1; off < 64; off <<= 1) {
            int u = __shfl_up(s, off, 64);
            if (lane >= off) s += u;
        }
        if (lane == 63) wsum[w] = s;
        __syncthreads();
        int wbase = 0;
        for (int k = 0; k < w; ++k) wbase += wsum[k];
        int e0 = wbase + s - tsum;
        int e1 = e0 + v0, e2 = e1 + v1, e3 = e2 + v2;
        if (idx0 + 0 < NB) { bstart[idx0 + 0] = e0; gcursor[idx0 + 0] = e0; }
        if (idx0 + 1 < NB) { bstart[idx0 + 1] = e1; gcursor[idx0 + 1] = e1; }
        if (idx0 + 2 < NB) { bstart[idx0 + 2] = e2; gcursor[idx0 + 2] = e2; }
        if (idx0 + 3 < NB) { bstart[idx0 + 3] = e3; gcursor[idx0 + 3] = e3; }
        if (tid == 0) {
            bstart[NB] = wsum[0] + wsum[1] + wsum[2] + wsum[3];
            nodestart[N] = E;
        }
        __threadfence();
        __syncthreads();
        if (tid == 0) atomicExch(scan_done, 1);
    } else {
        if (tid == 0) {
            while (atomicAdd(scan_done, 0) == 0) { __builtin_amdgcn_s_sleep(1); }
        }
        __syncthreads();
    }

    // ---- phase 2: reserve per-bucket ranges, scatter packed entries ----
    for (int i = tid; i < NB; i += 256) {
        int h = hist[i];
        cur[i] = h ? atomicAdd(&gcursor[i], h) : 0;
    }
    __syncthreads();
#pragma unroll
    for (int k = 0; k < 4; ++k) {
        int i4 = base + k * 256 + tid;
        if (i4 < E4) {
            int4 sv = ((const int4*)src)[i4];
            int4 d = dreg[k];
            int p;
            p = atomicAdd(&cur[d.x >> 7], 1); packed[p] = ((d.x & 127) << 20) | sv.x;
            p = atomicAdd(&cur[d.y >> 7], 1); packed[p] = ((d.y & 127) << 20) | sv.y;
            p = atomicAdd(&cur[d.z >> 7], 1); packed[p] = ((d.z & 127) << 20) | sv.z;
            p = atomicAdd(&cur[d.w >> 7], 1); packed[p] = ((d.w & 127) << 20) | sv.w;
        }
    }
}

// ---------------------------------------------------------------------------
// K_xform: y1 = x @ w1_l (bf16 out), z1 = x @ w1_r (f32 out)
// 128 rows/block; x staged in LDS as packed bf16 pairs (32 KB); each lane
// owns 2 rows x 8 outputs. Per 2 d's: 2 ds_read_b32 (xv pairs) +
// 4 ds_read_b128 (weights) + 32 FMA per lane -> ~0.93 LDS-cyc/row/d.
// ---------------------------------------------------------------------------
__global__ __launch_bounds__(256) void k_xform(const float* __restrict__ x,
                                               const float* __restrict__ w1l,
                                               const float* __restrict__ w1r,
                                               unsigned* __restrict__ y1b,
                                               float* __restrict__ z1, int N) {
    __shared__ float wl[DD * HH];          // 8 KB, [d*16 + j]
    __shared__ float wr[DD * HH];          // 8 KB
    __shared__ unsigned xt[128 * 66];      // 33 KB, bf16 pairs, row stride 66 u32

    const int tid  = threadIdx.x;
    const int row0 = blockIdx.x * 128;

    {
        const float4* a = (const float4*)w1l;
        const float4* b = (const float4*)w1r;
        ((float4*)wl)[tid]       = a[tid];
        ((float4*)wl)[tid + 256] = a[tid + 256];
        ((float4*)wr)[tid]       = b[tid];
        ((float4*)wr)[tid + 256] = b[tid + 256];
    }
#pragma unroll
    for (int k = 0; k < 16; ++k) {         // 128 rows x 32 f4 = 4096 f4
        int idx = tid + k * 256;
        int r = idx >> 5, c = idx & 31;
        if (row0 + r < N) {
            float4 v = ((const float4*)(x + (size_t)(row0 + r) * DD))[c];
            xt[r * 66 + 2 * c]     = pack2(v.x, v.y);
            xt[r * 66 + 2 * c + 1] = pack2(v.z, v.w);
        }
    }
    __syncthreads();

    const int r0 = tid >> 2, seg = tid & 3;   // r0 in [0,64)
    const int r1 = r0 + 64;
    const bool ok0 = (row0 + r0 < N), ok1 = (row0 + r1 < N);
    float4 ya = {0.f,0.f,0.f,0.f}, za = {0.f,0.f,0.f,0.f};
    float4 yb = {0.f,0.f,0.f,0.f}, zb = {0.f,0.f,0.f,0.f};
    const unsigned* xr0 = &xt[r0 * 66];
    const unsigned* xr1 = &xt[r1 * 66];
#pragma unroll 16
    for (int i = 0; i < 64; ++i) {
        unsigned p0 = xr0[i];
        unsigned p1 = xr1[i];
        const int d0 = 2 * i, d1 = 2 * i + 1;
        float4 wl0 = *(const float4*)&wl[d0 * HH + seg * 4];
        float4 wr0 = *(const float4*)&wr[d0 * HH + seg * 4];
        float4 wl1 = *(const float4*)&wl[d1 * HH + seg * 4];
        float4 wr1 = *(const float4*)&wr[d1 * HH + seg * 4];
        float xa = lo16(p0), xb2 = hi16(p0);
        float xc = lo16(p1), xd = hi16(p1);
        ya.x += xa*wl0.x + xb2*wl1.x;  ya.y += xa*wl0.y + xb2*wl1.y;
        ya.z += xa*wl0.z + xb2*wl1.z;  ya.w += xa*wl0.w + xb2*wl1.w;
        za.x += xa*wr0.x + xb2*wr1.x;  za.y += xa*wr0.y + xb2*wr1.y;
        za.z += xa*wr0.z + xb2*wr1.z;  za.w += xa*wr0.w + xb2*wr1.w;
        yb.x += xc*wl0.x + xd*wl1.x;   yb.y += xc*wl0.y + xd*wl1.y;
        yb.z += xc*wl0.z + xd*wl1.z;   yb.w += xc*wl0.w + xd*wl1.w;
        zb.x += xc*wr0.x + xd*wr1.x;   zb.y += xc*wr0.y + xd*wr1.y;
        zb.z += xc*wr0.z + xd*wr1.z;   zb.w += xc*wr0.w + xd*wr1.w;
    }
    if (ok0) {
        uint2 yp; yp.x = pack2(ya.x, ya.y); yp.y = pack2(ya.z, ya.w);
        ((uint2*)y1b)[(size_t)(row0 + r0) * 4 + seg] = yp;
        ((float4*)z1)[(size_t)(row0 + r0) * 4 + seg] = za;
    }
    if (ok1) {
        uint2 yp; yp.x = pack2(yb.x, yb.y); yp.y = pack2(yb.z, yb.w);
        ((uint2*)y1b)[(size_t)(row0 + r1) * 4 + seg] = yp;
        ((float4*)z1)[(size_t)(row0 + r1) * 4 + seg] = zb;
    }
}

// ---------------------------------------------------------------------------
// K_sortagg: one block per bucket.
//   Phase A: counting-sort the bucket slice in LDS, write nodestart + csr.
//   Phase B: layer-1 mean for the bucket's 128 nodes from the LDS-sorted
//            slice, gathering bf16 y1 (8 B/gather):
//            h = relu(mean(y1[nbrs]) + b1 + z1), h stored bf16.
// Global fallback for oversized buckets.
// ---------------------------------------------------------------------------
__global__ __launch_bounds__(256) void k_sortagg(const int* __restrict__ packed,
                                                 const int* __restrict__ bstart,
                                                 int* __restrict__ nodestart,
                                                 int* __restrict__ csr,
                                                 const unsigned* __restrict__ y1b,
                                                 const float* __restrict__ z1,
                                                 const float* __restrict__ b1,
                                                 unsigned* __restrict__ hb, int N) {
    __shared__ int buf[SCAP];
    __shared__ int sbuf[SCAP];
    __shared__ int hist[BW];
    __shared__ int exs[BW];
    __shared__ int curs[BW];
    __shared__ int wtot;
    const int tid = threadIdx.x;
    const int b = blockIdx.x;
    const int st = bstart[b], en = bstart[b + 1], cnt = en - st;
    const bool inlds = (cnt <= SCAP);

    if (tid < BW) hist[tid] = 0;
    __syncthreads();
    if (inlds) {
        for (int i = tid; i < cnt; i += 256) {
            int e = packed[st + i];
            buf[i] = e;
            atomicAdd(&hist[e >> 20], 1);
        }
    } else {
        for (int i = tid; i < cnt; i += 256)
            atomicAdd(&hist[packed[st + i] >> 20], 1);
    }
    __syncthreads();

    int v = 0, s = 0;
    if (tid < BW) {
        int lane = tid & 63;
        v = hist[tid];
        s = v;
#pragma unroll
        for (int off = 1; off < 64; off <<= 1) {
            int u = __shfl_up(s, off, 64);
            if (lane >= off) s += u;
        }
        if (tid == 63) wtot = s;
    }
    __syncthreads();
    if (tid < BW) {
        int ex = s - v + ((tid >= 64) ? wtot : 0);
        exs[tid] = ex;
        curs[tid] = ex;
        int node = (b << 7) + tid;
        if (node < N) nodestart[node] = st + ex;
    }
    __syncthreads();

    if (inlds) {
        for (int i = tid; i < cnt; i += 256) {
            int e = buf[i];
            int p = atomicAdd(&curs[e >> 20], 1);
            sbuf[p] = e & 0xFFFFF;
        }
        __syncthreads();
        for (int i = tid; i < cnt; i += 256) csr[st + i] = sbuf[i];  // coalesced
    } else {
        for (int i = tid; i < cnt; i += 256) {
            int e = packed[st + i];
            int p = atomicAdd(&curs[e >> 20], 1);
            csr[st + p] = e & 0xFFFFF;
        }
        __threadfence_block();
        __syncthreads();
    }

    // ---- Phase B: aggregate 128 nodes (4 lanes/node, 2 halves) ----
    const uint2* f2 = (const uint2*)y1b;
#pragma unroll
    for (int half = 0; half < 2; ++half) {
        int l = (tid >> 2) + half * 64;
        int seg = tid & 3;
        int node = (b << 7) + l;
        if (node < N) {
            int s0 = exs[l], c = hist[l];
            float ax = 0.f, ay = 0.f, az = 0.f, aw = 0.f;
            int k = 0;
            if (inlds) {
                for (; k + 4 <= c; k += 4) {
                    uint2 a = f2[(size_t)(sbuf[s0 + k]     * 4 + seg)];
                    uint2 bv = f2[(size_t)(sbuf[s0 + k + 1] * 4 + seg)];
                    uint2 cv = f2[(size_t)(sbuf[s0 + k + 2] * 4 + seg)];
                    uint2 dv = f2[(size_t)(sbuf[s0 + k + 3] * 4 + seg)];
                    ax += (lo16(a.x) + lo16(bv.x)) + (lo16(cv.x) + lo16(dv.x));
                    ay += (hi16(a.x) + hi16(bv.x)) + (hi16(cv.x) + hi16(dv.x));
                    az += (lo16(a.y) + lo16(bv.y)) + (lo16(cv.y) + lo16(dv.y));
                    aw += (hi16(a.y) + hi16(bv.y)) + (hi16(cv.y) + hi16(dv.y));
                }
                for (; k < c; ++k) {
                    uint2 a = f2[(size_t)(sbuf[s0 + k] * 4 + seg)];
                    ax += lo16(a.x); ay += hi16(a.x);
                    az += lo16(a.y); aw += hi16(a.y);
                }
            } else {
                const int* ids = csr + st + s0;
                for (; k + 4 <= c; k += 4) {
                    uint2 a = f2[(size_t)(ids[k]     * 4 + seg)];
                    uint2 bv = f2[(size_t)(ids[k + 1] * 4 + seg)];
                    uint2 cv = f2[(size_t)(ids[k + 2] * 4 + seg)];
                    uint2 dv = f2[(size_t)(ids[k + 3] * 4 + seg)];
                    ax += (lo16(a.x) + lo16(bv.x)) + (lo16(cv.x) + lo16(dv.x));
                    ay += (hi16(a.x) + hi16(bv.x)) + (hi16(cv.x) + hi16(dv.x));
                    az += (lo16(a.y) + lo16(bv.y)) + (lo16(cv.y) + lo16(dv.y));
                    aw += (hi16(a.y) + hi16(bv.y)) + (hi16(cv.y) + hi16(dv.y));
                }
                for (; k < c; ++k) {
                    uint2 a = f2[(size_t)(ids[k] * 4 + seg)];
                    ax += lo16(a.x); ay += hi16(a.x);
                    az += lo16(a.y); aw += hi16(a.y);
                }
            }
            float inv = 1.f / fmaxf((float)c, 1.f);
            size_t o = (size_t)node * 4 + seg;
            float4 z = ((const float4*)z1)[o];
            float4 bb = ((const float4*)b1)[seg];
            float hx = fmaxf(ax * inv + bb.x + z.x, 0.f);
            float hy = fmaxf(ay * inv + bb.y + z.y, 0.f);
            float hz = fmaxf(az * inv + bb.z + z.z, 0.f);
            float hw = fmaxf(aw * inv + bb.w + z.w, 0.f);
            uint2 hp; hp.x = pack2(hx, hy); hp.y = pack2(hz, hw);
            ((uint2*)hb)[o] = hp;
        }
    }
}

// ---------------------------------------------------------------------------
// K_pair: fused layer-2 on-demand aggregation + pair logits + BCE + final
// mean (ticket). 8 lanes per pair: slot s=sub>>2 (article), seg=sub&3.
// ---------------------------------------------------------------------------
__global__ __launch_bounds__(256) void k_pair(const unsigned* __restrict__ hb,
                                              const int* __restrict__ csr,
                                              const int* __restrict__ nodestart,
                                              const int* __restrict__ a1,
                                              const int* __restrict__ a2,
                                              const int* __restrict__ labels,
                                              const float* __restrict__ wsu,
                                              float* __restrict__ out_logits,
                                              float* __restrict__ lacc,
                                              int* __restrict__ ticket,
                                              float* __restrict__ out0,
                                              int B, float invB) {
    __shared__ float lred[32];
    int t = blockIdx.x * 256 + threadIdx.x;
    int p = t >> 3, sub = t & 7;
    int s = sub >> 2, seg = sub & 3;
    int g = threadIdx.x >> 3;
    const uint2* h2 = (const uint2*)hb;
    const float4* wsu4 = (const float4*)wsu;

    float myloss = 0.f;
    if (p < B) {
        int node = s ? a2[p] : a1[p];
        int st = nodestart[node], en = nodestart[node + 1];
        float ax = 0.f, ay = 0.f, az = 0.f, aw = 0.f;
        int k = st;
        for (; k + 2 <= en; k += 2) {
            uint2 a = h2[(size_t)(csr[k]     * 4 + seg)];
            uint2 b = h2[(size_t)(csr[k + 1] * 4 + seg)];
            ax += lo16(a.x) + lo16(b.x); ay += hi16(a.x) + hi16(b.x);
            az += lo16(a.y) + lo16(b.y); aw += hi16(a.y) + hi16(b.y);
        }
        if (k < en) {
            uint2 a = h2[(size_t)(csr[k] * 4 + seg)];
            ax += lo16(a.x); ay += hi16(a.x);
            az += lo16(a.y); aw += hi16(a.y);
        }
        float inv = 1.f / fmaxf((float)(en - st), 1.f);
        float4 ul = wsu4[s * 4 + seg];
        float4 ur = wsu4[8 + s * 4 + seg];
        uint2 hn = h2[(size_t)node * 4 + seg];
        float v = (ax * ul.x + ay * ul.y + az * ul.z + aw * ul.w) * inv
                + (lo16(hn.x) * ur.x + hi16(hn.x) * ur.y
                 + lo16(hn.y) * ur.z + hi16(hn.y) * ur.w);
#pragma unroll
        for (int off = 4; off; off >>= 1) v += __shfl_xor(v, off, 8);
        if (sub == 0) {
            float l = v + wsu[64] + wsu[65];
            out_logits[p] = l;
            float y = (float)labels[p];
            myloss = fmaxf(l, 0.f) - l * y + log1pf(expf(-fabsf(l)));
        }
    }
    if (sub == 0) lred[g] = myloss;
    __syncthreads();
    if (threadIdx.x == 0) {
        float ssum = 0.f;
#pragma unroll
        for (int k = 0; k < 32; ++k) ssum += lred[k];
        atomicAdd(lacc, ssum);
        __threadfence();
        int tk = atomicAdd(ticket, 1);
        if (tk == (int)gridDim.x - 1) {
            __threadfence();
            float total = atomicAdd(lacc, 0.f);
            out0[0] = total * invB;
        }
    }
}

// ---------------------------------------------------------------------------
extern "C" void kernel_launch(void* const* d_in, const int* in_sizes, int n_in,
                              void* d_out, int out_size, void* d_ws, size_t ws_size,
                              hipStream_t stream) {
    const float* x    = (const float*)d_in[0];
    const float* w1l  = (const float*)d_in[1];
    const float* b1   = (const float*)d_in[2];
    const float* w1r  = (const float*)d_in[3];
    const float* w2l  = (const float*)d_in[4];
    const float* b2v  = (const float*)d_in[5];
    const float* w2r  = (const float*)d_in[6];
    const float* wc   = (const float*)d_in[7];
    const float* bc   = (const float*)d_in[8];
    const int*   ei   = (const int*)d_in[9];
    const int*   a1   = (const int*)d_in[10];
    const int*   a2   = (const int*)d_in[11];
    const int*   lab  = (const int*)d_in[12];

    const int N = in_sizes[0] / DD;
    const int E = in_sizes[9] / 2;
    const int B = in_sizes[10];
    const int NB = (N + BW - 1) / BW;       // 782 for N=100000 (needs N < 2^20)

    const int* src = ei;
    const int* dst = ei + E;

    // workspace layout
    char* ws = (char*)d_ws;
    float*    wsu    = (float*)ws;                            // 512 B
    unsigned* y1b    = (unsigned*)(ws + 512);                 // [N,16] bf16 (32 B/row)
    unsigned* hb     = (unsigned*)(ws + 512 + (size_t)N * 32);
    float*    z1     = (float*)   (ws + 512 + (size_t)N * 64);
    int*      packed = (int*)     (ws + 512 + (size_t)N * 128);
    int*      csr    = (int*)     (ws + 512 + (size_t)N * 128 + (size_t)E * 4);
    char*     p4     = ws + 512 + (size_t)N * 128 + 2 * (size_t)E * 4;
    int*   nodest  = (int*)p4;                               // [N+1]
    int*   bstart  = (int*)(p4 + ((size_t)N + 1) * 4);       // [NB+1]
    int*   gcursor = (int*)(p4 + ((size_t)N + 1) * 4 + ((size_t)NB + 1) * 4);  // [NB]
    int*   bcnt    = (int*)(p4 + ((size_t)N + 1) * 4 + (2 * (size_t)NB + 1) * 4); // [NB] zeroed
    float* lacc    = (float*)(p4 + ((size_t)N + 1) * 4 + (3 * (size_t)NB + 1) * 4);// zeroed
    int*   ticket  = (int*)((char*)lacc + 4);                // zeroed (k_pair)
    int*   ticket2 = (int*)((char*)lacc + 8);                // zeroed (k_build)
    int*   sdone   = (int*)((char*)lacc + 12);               // zeroed (k_build)

    float* out = (float*)d_out;       // out[0] = loss, out[1..B] = logits

    hipMemsetAsync((void*)bcnt, 0, (size_t)NB * 4 + 16, stream);

    const int E4 = E / 4;
    const int cblocks = (E4 + 1023) / 1024;          // 4096 edges per chunk

    k_build<<<cblocks + 1, 256, 0, stream>>>(src, dst, bcnt, bstart, gcursor,
                                             nodest, packed, ticket2, sdone,
                                             E4, NB, cblocks, N, E,
                                             w2l, w2r, b2v, wc, bc, wsu);

    k_xform<<<(N + 127) / 128, 256, 0, stream>>>(x, w1l, w1r, y1b, z1, N);

    k_sortagg<<<NB, 256, 0, stream>>>(packed, bstart, nodest, csr, y1b, z1, b1, hb, N);

    k_pair<<<(B * 8 + 255) / 256, 256, 0, stream>>>(hb, csr, nodest, a1, a2, lab, wsu,
                                                    out + 1, lacc, ticket, out,
                                                    B, 1.0f / (float)B);
}

// Round 11
// 224.539 us; speedup vs baseline: 1.1831x; 1.1831x over previous
//
#include <hip/hip_runtime.h>
#include <hip/hip_bf16.h>

#define DD 128    // feature dim
#define HH 16     // hidden dim
#define BW 128    // bucket width (nodes per bucket) = 1<<7
#define NBMAX 1024
#define SCAP 4096      // LDS slice cap in sortagg (avg slice 2048, max ~2300)

// bf16x2 pack/unpack (RNE)
__device__ __forceinline__ float lo16(unsigned u) { return __uint_as_float(u << 16); }
__device__ __forceinline__ float hi16(unsigned u) { return __uint_as_float(u & 0xffff0000u); }
__device__ __forceinline__ unsigned b16(float f) {
    unsigned u = __float_as_uint(f);
    return (u + 0x7fffu + ((u >> 16) & 1u)) >> 16;
}
__device__ __forceinline__ unsigned pack2(float a, float b) {
    return b16(a) | (b16(b) << 16);
}

// ---------------------------------------------------------------------------
// K1: bucket histogram (4096 edges/block) + classifier-collapse prep (last
// block).
//   wsu[0..15]  = w2_l[j,:].wc[:128]    wsu[16..31] = w2_l[j,:].wc[128:]
//   wsu[32..47] = w2_r[j,:].wc[:128]    wsu[48..63] = w2_r[j,:].wc[128:]
//   wsu[64] = b2.wc[:128] + bc ;  wsu[65] = b2.wc[128:]
// ---------------------------------------------------------------------------
__global__ __launch_bounds__(256) void k_bcount(const int* __restrict__ dst,
                                                int* __restrict__ bcnt,
                                                int E4, int NB, int cblocks,
                                                const float* __restrict__ w2l,
                                                const float* __restrict__ w2r,
                                                const float* __restrict__ b2v,
                                                const float* __restrict__ wc,
                                                const float* __restrict__ bc,
                                                float* __restrict__ wsu) {
    if (blockIdx.x == (unsigned)cblocks) {      // prep block
        int t = threadIdx.x;
        if (t < 64) {
            int k = t >> 4, j = t & 15;
            const float* W = (k < 2) ? w2l : w2r;
            int off = (k & 1) * DD;
            float s = 0.f;
            for (int d = 0; d < DD; ++d) s += W[j * DD + d] * wc[off + d];
            wsu[k * 16 + j] = s;
        } else if (t == 64) {
            float s = bc[0];
            for (int d = 0; d < DD; ++d) s += b2v[d] * wc[d];
            wsu[64] = s;
        } else if (t == 65) {
            float s = 0.f;
            for (int d = 0; d < DD; ++d) s += b2v[d] * wc[DD + d];
            wsu[65] = s;
        }
        return;
    }
    __shared__ int hist[NBMAX];
    for (int i = threadIdx.x; i < NB; i += 256) hist[i] = 0;
    __syncthreads();
    int base = blockIdx.x * 1024;
#pragma unroll
    for (int k = 0; k < 4; ++k) {
        int i4 = base + k * 256 + threadIdx.x;
        if (i4 < E4) {
            int4 d = ((const int4*)dst)[i4];
            atomicAdd(&hist[d.x >> 7], 1);
            atomicAdd(&hist[d.y >> 7], 1);
            atomicAdd(&hist[d.z >> 7], 1);
            atomicAdd(&hist[d.w >> 7], 1);
        }
    }
    __syncthreads();
    for (int i = threadIdx.x; i < NB; i += 256) {
        int h = hist[i];
        if (h) atomicAdd(&bcnt[i], h);
    }
}

// ---------------------------------------------------------------------------
// K2: exclusive scan over NB bucket counts -> bstart (+[NB]=E), gcursor;
// also nodestart[N] = E. Single block of 1024.
// ---------------------------------------------------------------------------
__global__ __launch_bounds__(1024) void k_bscan(const int* __restrict__ bcnt,
                                                int* __restrict__ bstart,
                                                int* __restrict__ gcursor,
                                                int* __restrict__ nodestart,
                                                int NB, int N, int E) {
    __shared__ int sa[1024];
    __shared__ int sb[1024];
    int t = threadIdx.x;
    int v = (t < NB) ? bcnt[t] : 0;
    sa[t] = v;
    __syncthreads();
    int* cur = sa;
    int* nxt = sb;
    for (int off = 1; off < 1024; off <<= 1) {
        int xv = cur[t];
        if (t >= off) xv += cur[t - off];
        nxt[t] = xv;
        __syncthreads();
        int* tmp = cur; cur = nxt; nxt = tmp;
    }
    if (t < NB) {
        int excl = cur[t] - v;
        bstart[t] = excl;
        gcursor[t] = excl;
    }
    if (t == 0) {
        bstart[NB] = cur[1023];
        nodestart[N] = E;
    }
}

// ---------------------------------------------------------------------------
// K3: bucketed scatter (4096 edges/block). LDS hist -> bulk range
// reservation -> packed entries (local<<20 | src) into per-bucket ranges.
// ---------------------------------------------------------------------------
__global__ __launch_bounds__(256) void k_bscatter(const int* __restrict__ src,
                                                  const int* __restrict__ dst,
                                                  int* __restrict__ gcursor,
                                                  int* __restrict__ packed,
                                                  int E4, int NB) {
    __shared__ int hist[NBMAX];
    __shared__ int cur[NBMAX];
    for (int i = threadIdx.x; i < NB; i += 256) hist[i] = 0;
    __syncthreads();
    int base = blockIdx.x * 1024;
    int4 dreg[4];
#pragma unroll
    for (int k = 0; k < 4; ++k) {
        int i4 = base + k * 256 + threadIdx.x;
        if (i4 < E4) {
            int4 d = ((const int4*)dst)[i4];
            dreg[k] = d;
            atomicAdd(&hist[d.x >> 7], 1);
            atomicAdd(&hist[d.y >> 7], 1);
            atomicAdd(&hist[d.z >> 7], 1);
            atomicAdd(&hist[d.w >> 7], 1);
        }
    }
    __syncthreads();
    for (int i = threadIdx.x; i < NB; i += 256) {
        int hv = hist[i];
        cur[i] = hv ? atomicAdd(&gcursor[i], hv) : 0;
    }
    __syncthreads();
#pragma unroll
    for (int k = 0; k < 4; ++k) {
        int i4 = base + k * 256 + threadIdx.x;
        if (i4 < E4) {
            int4 sv = ((const int4*)src)[i4];
            int4 d = dreg[k];
            int p;
            p = atomicAdd(&cur[d.x >> 7], 1); packed[p] = ((d.x & 127) << 20) | sv.x;
            p = atomicAdd(&cur[d.y >> 7], 1); packed[p] = ((d.y & 127) << 20) | sv.y;
            p = atomicAdd(&cur[d.z >> 7], 1); packed[p] = ((d.z & 127) << 20) | sv.z;
            p = atomicAdd(&cur[d.w >> 7], 1); packed[p] = ((d.w & 127) << 20) | sv.w;
        }
    }
}

// ---------------------------------------------------------------------------
// K4: y1 = x @ w1_l (bf16 out), z1 = x @ w1_r (f32 out)
// 128 rows/block; x staged in LDS as packed bf16 pairs (33 KB); each lane
// owns 2 rows x 8 outputs. Per 2 d's: 2 ds_read_b32 (xv pairs) +
// 4 ds_read_b128 (weights, 4 distinct addrs/wave -> broadcast) + 32 FMA.
// ---------------------------------------------------------------------------
__global__ __launch_bounds__(256) void k_xform(const float* __restrict__ x,
                                               const float* __restrict__ w1l,
                                               const float* __restrict__ w1r,
                                               unsigned* __restrict__ y1b,
                                               float* __restrict__ z1, int N) {
    __shared__ float wl[DD * HH];          // 8 KB, [d*16 + j]
    __shared__ float wr[DD * HH];          // 8 KB
    __shared__ unsigned xt[128 * 66];      // 33 KB, bf16 pairs, row stride 66 u32

    const int tid  = threadIdx.x;
    const int row0 = blockIdx.x * 128;

    {
        const float4* a = (const float4*)w1l;
        const float4* b = (const float4*)w1r;
        ((float4*)wl)[tid]       = a[tid];
        ((float4*)wl)[tid + 256] = a[tid + 256];
        ((float4*)wr)[tid]       = b[tid];
        ((float4*)wr)[tid + 256] = b[tid + 256];
    }
#pragma unroll
    for (int k = 0; k < 16; ++k) {         // 128 rows x 32 f4 = 4096 f4
        int idx = tid + k * 256;
        int r = idx >> 5, c = idx & 31;
        if (row0 + r < N) {
            float4 v = ((const float4*)(x + (size_t)(row0 + r) * DD))[c];
            xt[r * 66 + 2 * c]     = pack2(v.x, v.y);
            xt[r * 66 + 2 * c + 1] = pack2(v.z, v.w);
        }
    }
    __syncthreads();

    const int r0 = tid >> 2, seg = tid & 3;   // r0 in [0,64)
    const int r1 = r0 + 64;
    const bool ok0 = (row0 + r0 < N), ok1 = (row0 + r1 < N);
    float4 ya = {0.f,0.f,0.f,0.f}, za = {0.f,0.f,0.f,0.f};
    float4 yb = {0.f,0.f,0.f,0.f}, zb = {0.f,0.f,0.f,0.f};
    const unsigned* xr0 = &xt[r0 * 66];
    const unsigned* xr1 = &xt[r1 * 66];
#pragma unroll 16
    for (int i = 0; i < 64; ++i) {
        unsigned p0 = xr0[i];
        unsigned p1 = xr1[i];
        const int d0 = 2 * i, d1 = 2 * i + 1;
        float4 wl0 = *(const float4*)&wl[d0 * HH + seg * 4];
        float4 wr0 = *(const float4*)&wr[d0 * HH + seg * 4];
        float4 wl1 = *(const float4*)&wl[d1 * HH + seg * 4];
        float4 wr1 = *(const float4*)&wr[d1 * HH + seg * 4];
        float xa = lo16(p0), xb2 = hi16(p0);
        float xc = lo16(p1), xd = hi16(p1);
        ya.x += xa*wl0.x + xb2*wl1.x;  ya.y += xa*wl0.y + xb2*wl1.y;
        ya.z += xa*wl0.z + xb2*wl1.z;  ya.w += xa*wl0.w + xb2*wl1.w;
        za.x += xa*wr0.x + xb2*wr1.x;  za.y += xa*wr0.y + xb2*wr1.y;
        za.z += xa*wr0.z + xb2*wr1.z;  za.w += xa*wr0.w + xb2*wr1.w;
        yb.x += xc*wl0.x + xd*wl1.x;   yb.y += xc*wl0.y + xd*wl1.y;
        yb.z += xc*wl0.z + xd*wl1.z;   yb.w += xc*wl0.w + xd*wl1.w;
        zb.x += xc*wr0.x + xd*wr1.x;   zb.y += xc*wr0.y + xd*wr1.y;
        zb.z += xc*wr0.z + xd*wr1.z;   zb.w += xc*wr0.w + xd*wr1.w;
    }
    if (ok0) {
        uint2 yp; yp.x = pack2(ya.x, ya.y); yp.y = pack2(ya.z, ya.w);
        ((uint2*)y1b)[(size_t)(row0 + r0) * 4 + seg] = yp;
        ((float4*)z1)[(size_t)(row0 + r0) * 4 + seg] = za;
    }
    if (ok1) {
        uint2 yp; yp.x = pack2(yb.x, yb.y); yp.y = pack2(yb.z, yb.w);
        ((uint2*)y1b)[(size_t)(row0 + r1) * 4 + seg] = yp;
        ((float4*)z1)[(size_t)(row0 + r1) * 4 + seg] = zb;
    }
}

// ---------------------------------------------------------------------------
// K5: one block per bucket.
//   Phase A: counting-sort the bucket slice in LDS, write nodestart + csr.
//   Phase B: layer-1 mean for the bucket's 128 nodes from the LDS-sorted
//            slice, gathering bf16 y1 (8 B/gather):
//            h = relu(mean(y1[nbrs]) + b1 + z1), h stored bf16.
// Global fallback for oversized buckets.
// ---------------------------------------------------------------------------
__global__ __launch_bounds__(256) void k_sortagg(const int* __restrict__ packed,
                                                 const int* __restrict__ bstart,
                                                 int* __restrict__ nodestart,
                                                 int* __restrict__ csr,
                                                 const unsigned* __restrict__ y1b,
                                                 const float* __restrict__ z1,
                                                 const float* __restrict__ b1,
                                                 unsigned* __restrict__ hb, int N) {
    __shared__ int buf[SCAP];
    __shared__ int sbuf[SCAP];
    __shared__ int hist[BW];
    __shared__ int exs[BW];
    __shared__ int curs[BW];
    __shared__ int wtot;
    const int tid = threadIdx.x;
    const int b = blockIdx.x;
    const int st = bstart[b], en = bstart[b + 1], cnt = en - st;
    const bool inlds = (cnt <= SCAP);

    if (tid < BW) hist[tid] = 0;
    __syncthreads();
    if (inlds) {
        for (int i = tid; i < cnt; i += 256) {
            int e = packed[st + i];
            buf[i] = e;
            atomicAdd(&hist[e >> 20], 1);
        }
    } else {
        for (int i = tid; i < cnt; i += 256)
            atomicAdd(&hist[packed[st + i] >> 20], 1);
    }
    __syncthreads();

    int v = 0, s = 0;
    if (tid < BW) {
        int lane = tid & 63;
        v = hist[tid];
        s = v;
#pragma unroll
        for (int off = 1; off < 64; off <<= 1) {
            int u = __shfl_up(s, off, 64);
            if (lane >= off) s += u;
        }
        if (tid == 63) wtot = s;
    }
    __syncthreads();
    if (tid < BW) {
        int ex = s - v + ((tid >= 64) ? wtot : 0);
        exs[tid] = ex;
        curs[tid] = ex;
        int node = (b << 7) + tid;
        if (node < N) nodestart[node] = st + ex;
    }
    __syncthreads();

    if (inlds) {
        for (int i = tid; i < cnt; i += 256) {
            int e = buf[i];
            int p = atomicAdd(&curs[e >> 20], 1);
            sbuf[p] = e & 0xFFFFF;
        }
        __syncthreads();
        for (int i = tid; i < cnt; i += 256) csr[st + i] = sbuf[i];  // coalesced
    } else {
        for (int i = tid; i < cnt; i += 256) {
            int e = packed[st + i];
            int p = atomicAdd(&curs[e >> 20], 1);
            csr[st + p] = e & 0xFFFFF;
        }
        __threadfence_block();
        __syncthreads();
    }

    // ---- Phase B: aggregate 128 nodes (4 lanes/node, 2 halves) ----
    const uint2* f2 = (const uint2*)y1b;
#pragma unroll
    for (int half = 0; half < 2; ++half) {
        int l = (tid >> 2) + half * 64;
        int seg = tid & 3;
        int node = (b << 7) + l;
        if (node < N) {
            int s0 = exs[l], c = hist[l];
            float ax = 0.f, ay = 0.f, az = 0.f, aw = 0.f;
            int k = 0;
            if (inlds) {
                for (; k + 4 <= c; k += 4) {
                    uint2 a = f2[(size_t)(sbuf[s0 + k]     * 4 + seg)];
                    uint2 bv = f2[(size_t)(sbuf[s0 + k + 1] * 4 + seg)];
                    uint2 cv = f2[(size_t)(sbuf[s0 + k + 2] * 4 + seg)];
                    uint2 dv = f2[(size_t)(sbuf[s0 + k + 3] * 4 + seg)];
                    ax += (lo16(a.x) + lo16(bv.x)) + (lo16(cv.x) + lo16(dv.x));
                    ay += (hi16(a.x) + hi16(bv.x)) + (hi16(cv.x) + hi16(dv.x));
                    az += (lo16(a.y) + lo16(bv.y)) + (lo16(cv.y) + lo16(dv.y));
                    aw += (hi16(a.y) + hi16(bv.y)) + (hi16(cv.y) + hi16(dv.y));
                }
                for (; k < c; ++k) {
                    uint2 a = f2[(size_t)(sbuf[s0 + k] * 4 + seg)];
                    ax += lo16(a.x); ay += hi16(a.x);
                    az += lo16(a.y); aw += hi16(a.y);
                }
            } else {
                const int* ids = csr + st + s0;
                for (; k + 4 <= c; k += 4) {
                    uint2 a = f2[(size_t)(ids[k]     * 4 + seg)];
                    uint2 bv = f2[(size_t)(ids[k + 1] * 4 + seg)];
                    uint2 cv = f2[(size_t)(ids[k + 2] * 4 + seg)];
                    uint2 dv = f2[(size_t)(ids[k + 3] * 4 + seg)];
                    ax += (lo16(a.x) + lo16(bv.x)) + (lo16(cv.x) + lo16(dv.x));
                    ay += (hi16(a.x) + hi16(bv.x)) + (hi16(cv.x) + hi16(dv.x));
                    az += (lo16(a.y) + lo16(bv.y)) + (lo16(cv.y) + lo16(dv.y));
                    aw += (hi16(a.y) + hi16(bv.y)) + (hi16(cv.y) + hi16(dv.y));
                }
                for (; k < c; ++k) {
                    uint2 a = f2[(size_t)(ids[k] * 4 + seg)];
                    ax += lo16(a.x); ay += hi16(a.x);
                    az += lo16(a.y); aw += hi16(a.y);
                }
            }
            float inv = 1.f / fmaxf((float)c, 1.f);
            size_t o = (size_t)node * 4 + seg;
            float4 z = ((const float4*)z1)[o];
            float4 bb = ((const float4*)b1)[seg];
            float hx = fmaxf(ax * inv + bb.x + z.x, 0.f);
            float hy = fmaxf(ay * inv + bb.y + z.y, 0.f);
            float hz = fmaxf(az * inv + bb.z + z.z, 0.f);
            float hw = fmaxf(aw * inv + bb.w + z.w, 0.f);
            uint2 hp; hp.x = pack2(hx, hy); hp.y = pack2(hz, hw);
            ((uint2*)hb)[o] = hp;
        }
    }
}

// ---------------------------------------------------------------------------
// K6: fused layer-2 on-demand aggregation + pair logits + BCE + final mean
// (ticket). 8 lanes per pair: slot s=sub>>2 (article), seg=sub&3. Gathers
// bf16 h (8 B per edge per lane).
// ---------------------------------------------------------------------------
__global__ __launch_bounds__(256) void k_pair(const unsigned* __restrict__ hb,
                                              const int* __restrict__ csr,
                                              const int* __restrict__ nodestart,
                                              const int* __restrict__ a1,
                                              const int* __restrict__ a2,
                                              const int* __restrict__ labels,
                                              const float* __restrict__ wsu,
                                              float* __restrict__ out_logits,
                                              float* __restrict__ lacc,
                                              int* __restrict__ ticket,
                                              float* __restrict__ out0,
                                              int B, float invB) {
    __shared__ float lred[32];
    int t = blockIdx.x * 256 + threadIdx.x;
    int p = t >> 3, sub = t & 7;
    int s = sub >> 2, seg = sub & 3;
    int g = threadIdx.x >> 3;
    const uint2* h2 = (const uint2*)hb;
    const float4* wsu4 = (const float4*)wsu;

    float myloss = 0.f;
    if (p < B) {
        int node = s ? a2[p] : a1[p];
        int st = nodestart[node], en = nodestart[node + 1];
        float ax = 0.f, ay = 0.f, az = 0.f, aw = 0.f;
        int k = st;
        for (; k + 2 <= en; k += 2) {
            uint2 a = h2[(size_t)(csr[k]     * 4 + seg)];
            uint2 b = h2[(size_t)(csr[k + 1] * 4 + seg)];
            ax += lo16(a.x) + lo16(b.x); ay += hi16(a.x) + hi16(b.x);
            az += lo16(a.y) + lo16(b.y); aw += hi16(a.y) + hi16(b.y);
        }
        if (k < en) {
            uint2 a = h2[(size_t)(csr[k] * 4 + seg)];
            ax += lo16(a.x); ay += hi16(a.x);
            az += lo16(a.y); aw += hi16(a.y);
        }
        float inv = 1.f / fmaxf((float)(en - st), 1.f);
        float4 ul = wsu4[s * 4 + seg];
        float4 ur = wsu4[8 + s * 4 + seg];
        uint2 hn = h2[(size_t)node * 4 + seg];
        float v = (ax * ul.x + ay * ul.y + az * ul.z + aw * ul.w) * inv
                + (lo16(hn.x) * ur.x + hi16(hn.x) * ur.y
                 + lo16(hn.y) * ur.z + hi16(hn.y) * ur.w);
#pragma unroll
        for (int off = 4; off; off >>= 1) v += __shfl_xor(v, off, 8);
        if (sub == 0) {
            float l = v + wsu[64] + wsu[65];
            out_logits[p] = l;
            float y = (float)labels[p];
            myloss = fmaxf(l, 0.f) - l * y + log1pf(expf(-fabsf(l)));
        }
    }
    if (sub == 0) lred[g] = myloss;
    __syncthreads();
    if (threadIdx.x == 0) {
        float ssum = 0.f;
#pragma unroll
        for (int k = 0; k < 32; ++k) ssum += lred[k];
        atomicAdd(lacc, ssum);
        __threadfence();
        int tk = atomicAdd(ticket, 1);
        if (tk == (int)gridDim.x - 1) {
            __threadfence();
            float total = atomicAdd(lacc, 0.f);
            out0[0] = total * invB;
        }
    }
}

// ---------------------------------------------------------------------------
extern "C" void kernel_launch(void* const* d_in, const int* in_sizes, int n_in,
                              void* d_out, int out_size, void* d_ws, size_t ws_size,
                              hipStream_t stream) {
    const float* x    = (const float*)d_in[0];
    const float* w1l  = (const float*)d_in[1];
    const float* b1   = (const float*)d_in[2];
    const float* w1r  = (const float*)d_in[3];
    const float* w2l  = (const float*)d_in[4];
    const float* b2v  = (const float*)d_in[5];
    const float* w2r  = (const float*)d_in[6];
    const float* wc   = (const float*)d_in[7];
    const float* bc   = (const float*)d_in[8];
    const int*   ei   = (const int*)d_in[9];
    const int*   a1   = (const int*)d_in[10];
    const int*   a2   = (const int*)d_in[11];
    const int*   lab  = (const int*)d_in[12];

    const int N = in_sizes[0] / DD;
    const int E = in_sizes[9] / 2;
    const int B = in_sizes[10];
    const int NB = (N + BW - 1) / BW;       // 782 for N=100000 (needs N < 2^20)

    const int* src = ei;
    const int* dst = ei + E;

    // workspace layout
    char* ws = (char*)d_ws;
    float*    wsu    = (float*)ws;                            // 512 B
    unsigned* y1b    = (unsigned*)(ws + 512);                 // [N,16] bf16 (32 B/row)
    unsigned* hb     = (unsigned*)(ws + 512 + (size_t)N * 32);
    float*    z1     = (float*)   (ws + 512 + (size_t)N * 64);
    int*      packed = (int*)     (ws + 512 + (size_t)N * 128);
    int*      csr    = (int*)     (ws + 512 + (size_t)N * 128 + (size_t)E * 4);
    char*     p4     = ws + 512 + (size_t)N * 128 + 2 * (size_t)E * 4;
    int*   nodest  = (int*)p4;                               // [N+1]
    int*   bstart  = (int*)(p4 + ((size_t)N + 1) * 4);       // [NB+1]
    int*   gcursor = (int*)(p4 + ((size_t)N + 1) * 4 + ((size_t)NB + 1) * 4);  // [NB]
    int*   bcnt    = (int*)(p4 + ((size_t)N + 1) * 4 + (2 * (size_t)NB + 1) * 4); // [NB] zeroed
    float* lacc    = (float*)(p4 + ((size_t)N + 1) * 4 + (3 * (size_t)NB + 1) * 4);// zeroed
    int*   ticket  = (int*)((char*)lacc + 4);                // zeroed

    float* out = (float*)d_out;       // out[0] = loss, out[1..B] = logits

    hipMemsetAsync((void*)bcnt, 0, (size_t)NB * 4 + 8, stream);

    const int E4 = E / 4;
    const int cblocks = (E4 + 1023) / 1024;          // 4096 edges per chunk

    k_bcount<<<cblocks + 1, 256, 0, stream>>>(dst, bcnt, E4, NB, cblocks,
                                              w2l, w2r, b2v, wc, bc, wsu);
    k_bscan<<<1, 1024, 0, stream>>>(bcnt, bstart, gcursor, nodest, NB, N, E);
    k_bscatter<<<cblocks, 256, 0, stream>>>(src, dst, gcursor, packed, E4, NB);

    k_xform<<<(N + 127) / 128, 256, 0, stream>>>(x, w1l, w1r, y1b, z1, N);

    k_sortagg<<<NB, 256, 0, stream>>>(packed, bstart, nodest, csr, y1b, z1, b1, hb, N);

    k_pair<<<(B * 8 + 255) / 256, 256, 0, stream>>>(hb, csr, nodest, a1, a2, lab, wsu,
                                                    out + 1, lacc, ticket, out,
                                                    B, 1.0f / (float)B);
}